// Round 5
// baseline (269.888 us; speedup 1.0000x reference)
//
#include <hip/hip_runtime.h>
#include <math.h>

#define BB     1024
#define CC     256
#define HWN    361
#define SEH    64
#define P3C    768
#define SLICE  (CC * HWN)     // 92416 floats per batch row
#define SLICE4 (SLICE / 4)    // 23104 float4s
#define NW     16             // waves per block

typedef float f32x4 __attribute__((ext_vector_type(4)));

// ---------------- Kernel A: pool + tiny MLP, one block (16 waves) per b ------
// Writes [sigmoid(gamma) | beta] (512 floats) per b into d_ws.
__global__ __launch_bounds__(1024, 2) void k_pool_mlp(
        const float* __restrict__ x,
        const float* __restrict__ mask,
        const float* __restrict__ msum,
        const float* __restrict__ msqrt,
        const float* __restrict__ w1,
        const float* __restrict__ b1,
        const float* __restrict__ w2,
        const float* __restrict__ b2,
        float* __restrict__ gb) {
    __shared__ float m_s[HWN];
    __shared__ float p_s[P3C];
    __shared__ float part_s[NW * SEH];
    __shared__ float hid_s[SEH];

    const int tid  = threadIdx.x;
    const int lane = tid & 63;
    const int wv   = tid >> 6;          // 0..15
    const int b    = blockIdx.x;

    const float* xb = x + (size_t)b * SLICE;

    if (tid < HWN) m_s[tid] = mask[(size_t)b * HWN + tid];
    __syncthreads();

    const float inv_div = 1.0f / msum[b];
    const float bscale  = (msqrt[b] - 14.0f) * 0.1f;   // (sqrt(div)-B_AVG)/10

    // ---- pool: wave wv owns rows c = wv*16 .. wv*16+15; 4 rows in flight ----
    #pragma unroll
    for (int k0 = 0; k0 < 16; k0 += 4) {
        float s[4], mx[4];
        #pragma unroll
        for (int q = 0; q < 4; ++q) { s[q] = 0.0f; mx[q] = -INFINITY; }
        #pragma unroll
        for (int q = 0; q < 4; ++q) {
            const float* xr = xb + (wv * 16 + k0 + q) * HWN;
            #pragma unroll
            for (int i = lane; i < HWN; i += 64) {
                float v = xr[i];
                s[q] += v;                                      // raw (unmasked) sum
                mx[q] = fmaxf(mx[q], fmaf(1.0f - m_s[i], -5000.0f, v));
            }
        }
        #pragma unroll
        for (int off = 32; off; off >>= 1) {
            #pragma unroll
            for (int q = 0; q < 4; ++q) {
                s[q]  += __shfl_xor(s[q], off);
                mx[q]  = fmaxf(mx[q], __shfl_xor(mx[q], off));
            }
        }
        if (lane == 0) {
            #pragma unroll
            for (int q = 0; q < 4; ++q) {
                const int c = wv * 16 + k0 + q;
                float mean = s[q] * inv_div;
                p_s[c]        = mean;
                p_s[256 + c]  = mean * bscale;
                p_s[512 + c]  = mx[q];
            }
        }
    }
    __syncthreads();

    // ---- layer 1 (768 -> 64): 16 partial dots (48 long) per output ----
    {
        const int q = tid >> 6, s = tid & 63;
        const float* w1r = w1  + s * P3C + q * 48;
        const float* pp  = p_s + q * 48;
        float acc = 0.0f;
        #pragma unroll 8
        for (int j = 0; j < 48; ++j) acc = fmaf(pp[j], w1r[j], acc);
        part_s[q * SEH + s] = acc;
    }
    __syncthreads();
    if (tid < SEH) {
        float h = b1[tid];
        #pragma unroll
        for (int q = 0; q < NW; ++q) h += part_s[q * SEH + tid];
        hid_s[tid] = fmaxf(h, 0.0f);
    }
    __syncthreads();

    // ---- layer 2 (64 -> 512); threads 0..511 -> [sig(gamma) | beta] ----
    if (tid < 512) {
        float a = b2[tid];
        const float* w2r = w2 + (size_t)tid * SEH;
        #pragma unroll 8
        for (int ss = 0; ss < SEH; ++ss) a = fmaf(hid_s[ss], w2r[ss], a);
        if (tid < 256) gb[(size_t)b * 512 + tid] = 1.0f / (1.0f + __expf(-a));
        else           gb[(size_t)b * 512 + tid] = a;
    }
}

// ---------------- Kernel B: apply, one block (16 waves) per b ----------------
__global__ __launch_bounds__(1024, 2) void k_apply(
        const float* __restrict__ x,
        const float* __restrict__ mask,
        const float* __restrict__ gb,
        float* __restrict__ out) {
    __shared__ float m_s[HWN];
    __shared__ float g_s[CC];
    __shared__ float be_s[CC];

    const int tid = threadIdx.x;
    const int b   = blockIdx.x;

    if (tid < HWN) m_s[tid] = mask[(size_t)b * HWN + tid];
    if (tid < 512) {
        float v = gb[(size_t)b * 512 + tid];
        if (tid < 256) g_s[tid]        = v;
        else           be_s[tid - 256] = v;
    }
    __syncthreads();

    const f32x4* x4 = (const f32x4*)(x   + (size_t)b * SLICE);
    f32x4*       o4 = (f32x4*)      (out + (size_t)b * SLICE);
    for (int i = tid; i < SLICE4; i += 1024) {
        f32x4 v = x4[i];
        const unsigned e0 = (unsigned)i * 4u;
        #pragma unroll
        for (int j = 0; j < 4; ++j) {
            unsigned e  = e0 + j;
            unsigned c  = e / 361u;            // compiler magic-mul
            unsigned hw = e - c * 361u;
            v[j] = fmaf(g_s[c], v[j], be_s[c]) * m_s[hw];
        }
        __builtin_nontemporal_store(v, &o4[i]);
    }
}

extern "C" void kernel_launch(void* const* d_in, const int* in_sizes, int n_in,
                              void* d_out, int out_size, void* d_ws, size_t ws_size,
                              hipStream_t stream) {
    const float* x     = (const float*)d_in[0];
    const float* mask  = (const float*)d_in[1];
    const float* msum  = (const float*)d_in[2];
    const float* msqrt = (const float*)d_in[3];
    const float* w1    = (const float*)d_in[4];
    const float* b1    = (const float*)d_in[5];
    const float* w2    = (const float*)d_in[6];
    const float* b2    = (const float*)d_in[7];
    float* out = (float*)d_out;

    float* gb = (float*)d_ws;   // B x [256 sig(gamma) | 256 beta]  (2 MB)

    k_pool_mlp<<<BB, 1024, 0, stream>>>(x, mask, msum, msqrt, w1, b1, w2, b2, gb);
    k_apply   <<<BB, 1024, 0, stream>>>(x, mask, gb, out);
}

// Round 6
// 236.075 us; speedup vs baseline: 1.1432x; 1.1432x over previous
//
#include <hip/hip_runtime.h>
#include <math.h>

#define BB     1024
#define CC     256
#define HWN    361
#define SEH    64
#define P3C    768
#define SLICE  (CC * HWN)     // 92416 floats per batch row
#define SLICE4 (SLICE / 4)    // 23104 float4s
#define NW     16             // waves per block

typedef float f32x4 __attribute__((ext_vector_type(4)));

// One block (16 waves) per batch row b; 2 blocks/CU resident (VGPR<=64).
// pool (4-row batches, 24 loads in flight) -> MLP in LDS -> apply (4-deep f4).
__global__ __launch_bounds__(1024, 8) void k_se_fused(
        const float* __restrict__ x,
        const float* __restrict__ mask,
        const float* __restrict__ msum,
        const float* __restrict__ msqrt,
        const float* __restrict__ w1,
        const float* __restrict__ b1,
        const float* __restrict__ w2,
        const float* __restrict__ b2,
        float* __restrict__ out) {
    __shared__ float m_s[HWN];
    __shared__ float p_s[P3C];
    __shared__ float part_s[NW * SEH];
    __shared__ float hid_s[SEH];
    __shared__ float g_s[CC];
    __shared__ float be_s[CC];

    const int tid  = threadIdx.x;
    const int lane = tid & 63;
    const int wv   = tid >> 6;          // 0..15
    const int b    = blockIdx.x;

    const float* xb = x + (size_t)b * SLICE;

    if (tid < HWN) m_s[tid] = mask[(size_t)b * HWN + tid];
    __syncthreads();

    const float inv_div = 1.0f / msum[b];
    const float bscale  = (msqrt[b] - 14.0f) * 0.1f;   // (sqrt(div)-B_AVG)/10

    // ---- pool: wave wv owns rows wv*16..wv*16+15, in 4 batches of 4 rows ----
    #pragma unroll
    for (int k0 = 0; k0 < 16; k0 += 4) {
        float s[4]  = {0.0f, 0.0f, 0.0f, 0.0f};
        float mx[4] = {-INFINITY, -INFINITY, -INFINITY, -INFINITY};
        const float* xr = xb + (wv * 16 + k0) * HWN;
        // 24 predicated loads issued back-to-back (ILP across 4 rows)
        #pragma unroll
        for (int ii = 0; ii < 6; ++ii) {
            const int i = lane + ii * 64;
            if (i < HWN) {
                const float pen = (1.0f - m_s[i]) * -5000.0f;
                #pragma unroll
                for (int q = 0; q < 4; ++q) {
                    float v = xr[q * HWN + i];
                    s[q]  += v;
                    mx[q]  = fmaxf(mx[q], v + pen);
                }
            }
        }
        // 8 independent butterfly chains, interleaved
        #pragma unroll
        for (int off = 32; off; off >>= 1) {
            #pragma unroll
            for (int q = 0; q < 4; ++q) {
                s[q]  += __shfl_xor(s[q], off);
                mx[q]  = fmaxf(mx[q], __shfl_xor(mx[q], off));
            }
        }
        if (lane == 0) {
            #pragma unroll
            for (int q = 0; q < 4; ++q) {
                const int c = wv * 16 + k0 + q;
                float mean = s[q] * inv_div;
                p_s[c]       = mean;
                p_s[256 + c] = mean * bscale;
                p_s[512 + c] = mx[q];
            }
        }
    }
    __syncthreads();

    // ---- layer 1 (768 -> 64): 16 partials (48 long) per output ----
    {
        const int q = tid >> 6, s = tid & 63;
        const float* w1r = w1  + s * P3C + q * 48;
        const float* pp  = p_s + q * 48;
        float acc = 0.0f;
        #pragma unroll 8
        for (int j = 0; j < 48; ++j) acc = fmaf(pp[j], w1r[j], acc);
        part_s[q * SEH + s] = acc;
    }
    __syncthreads();
    if (tid < SEH) {
        float h = b1[tid];
        #pragma unroll
        for (int q = 0; q < NW; ++q) h += part_s[q * SEH + tid];
        hid_s[tid] = fmaxf(h, 0.0f);
    }
    __syncthreads();

    // ---- layer 2 (64 -> 512) ----
    if (tid < 512) {
        float a = b2[tid];
        const float* w2r = w2 + (size_t)tid * SEH;
        #pragma unroll 8
        for (int ss = 0; ss < SEH; ++ss) a = fmaf(hid_s[ss], w2r[ss], a);
        if (tid < 256) g_s[tid]        = 1.0f / (1.0f + __expf(-a));
        else           be_s[tid - 256] = a;
    }
    __syncthreads();

    // ---- apply: 4-deep manual pipeline of float4 iters; NT stores ----
    const f32x4* x4 = (const f32x4*)xb;
    f32x4*       o4 = (f32x4*)(out + (size_t)b * SLICE);

    auto proc = [&](f32x4& v, unsigned i) {
        const unsigned e0 = i * 4u;
        #pragma unroll
        for (int j = 0; j < 4; ++j) {
            unsigned e  = e0 + j;
            unsigned c  = e / 361u;            // magic-mul
            unsigned hw = e - c * 361u;
            v[j] = fmaf(g_s[c], v[j], be_s[c]) * m_s[hw];
        }
    };

    unsigned i0 = tid;
    #pragma unroll 1
    for (int g = 0; g < 5; ++g) {             // 5 groups x 4 iters = 20 iters
        f32x4 v0 = x4[i0];
        f32x4 v1 = x4[i0 + 1024];
        f32x4 v2 = x4[i0 + 2048];
        f32x4 v3 = x4[i0 + 3072];
        proc(v0, i0); proc(v1, i0 + 1024); proc(v2, i0 + 2048); proc(v3, i0 + 3072);
        __builtin_nontemporal_store(v0, &o4[i0]);
        __builtin_nontemporal_store(v1, &o4[i0 + 1024]);
        __builtin_nontemporal_store(v2, &o4[i0 + 2048]);
        __builtin_nontemporal_store(v3, &o4[i0 + 3072]);
        i0 += 4096;
    }
    // tail: iters 20,21 full; iter 22 only for tid < 576   (23104 = 1024*22+576)
    {
        f32x4 v0 = x4[i0];
        f32x4 v1 = x4[i0 + 1024];
        proc(v0, i0); proc(v1, i0 + 1024);
        __builtin_nontemporal_store(v0, &o4[i0]);
        __builtin_nontemporal_store(v1, &o4[i0 + 1024]);
        i0 += 2048;
        if (tid < 576) {
            f32x4 v2 = x4[i0];
            proc(v2, i0);
            __builtin_nontemporal_store(v2, &o4[i0]);
        }
    }
}

extern "C" void kernel_launch(void* const* d_in, const int* in_sizes, int n_in,
                              void* d_out, int out_size, void* d_ws, size_t ws_size,
                              hipStream_t stream) {
    const float* x     = (const float*)d_in[0];
    const float* mask  = (const float*)d_in[1];
    const float* msum  = (const float*)d_in[2];
    const float* msqrt = (const float*)d_in[3];
    const float* w1    = (const float*)d_in[4];
    const float* b1    = (const float*)d_in[5];
    const float* w2    = (const float*)d_in[6];
    const float* b2    = (const float*)d_in[7];
    float* out = (float*)d_out;

    k_se_fused<<<BB, 1024, 0, stream>>>(x, mask, msum, msqrt, w1, b1, w2, b2, out);
}